// Round 5
// baseline (478.976 us; speedup 1.0000x reference)
//
#include <hip/hip_runtime.h>
#include <hip/hip_bf16.h>

#define NN 32
#define CIN 64
#define TTOT 300
#define VV 25
#define PP 3
#define COUT 128
#define KTOT 192     // P*CIN
#define TTILE 5
#define NTILES 60
#define CNT 240000.0f
#define NCOLS 240000 // N*T*V

#define XSTR 40      // X/At w-stride in shorts: 80B rows -> 2-way banks, 16B aligned
#define ZSTR 72      // fused-path Z2 c-stride
#define ZROWS 128

// ws float offsets (table region, < 1 MB)
#define WS_STATS 0    // 256 f32: sum[128], sumsq[128]
#define WS_SCALE 256  // 128 f32
#define WS_SHIFT 384  // 128 f32
#define WS_BSUM  512  // 128 f32
#define WS_W2    640  // bf16[128*192]; W2[o][p*64+c]
#define ZT_BYTE_OFF (1u << 20)                       // Zt bf16[240000][192] at +1MB
#define WS_NEEDED (ZT_BYTE_OFF + (size_t)NCOLS * KTOT * 2)

typedef float f32x4 __attribute__((ext_vector_type(4)));
typedef short s16x8 __attribute__((ext_vector_type(8)));

__device__ __forceinline__ short f2bf(float f) {
    unsigned u = __float_as_uint(f);
    u += 0x7fff + ((u >> 16) & 1);          // RNE
    return (short)(u >> 16);
}

__device__ __forceinline__ void gl_lds16(const void* g, void* l) {
    __builtin_amdgcn_global_load_lds(
        (const __attribute__((address_space(1))) unsigned int*)g,
        (__attribute__((address_space(3))) unsigned int*)l, 16, 0, 0);
}

__global__ __launch_bounds__(256) void prep_kernel(const float* __restrict__ W,
                                                   const float* __restrict__ b,
                                                   float* __restrict__ ws) {
    int tid = blockIdx.x * blockDim.x + threadIdx.x;
    if (tid < 256) ws[WS_STATS + tid] = 0.0f;               // zero stats every launch
    if (tid >= 256 && tid < 384) {
        int o = tid - 256;
        ws[WS_BSUM + o] = b[o] + b[COUT + o] + b[2 * COUT + o];
    }
    if (tid < COUT * KTOT) {                                 // W2[o][k], k = p*64+c
        int o = tid / KTOT, k = tid % KTOT;
        int p = k / 64, c = k % 64;
        ((short*)(ws + WS_W2))[tid] = f2bf(W[(p * COUT + o) * CIN + c]);
    }
}

// ---------------- two-kernel path ----------------

// Aggregation: Zt[col=(n*300+t)*25+v][k=p*64+c] = bf16( sum_w x[n,c,t,w]*A[p,w,v] )
// 33.3 KB LDS -> 4 blocks/CU; ONE barrier; 15 MFMA/wave.
__global__ __launch_bounds__(512, 4) void agg_kernel(const float* __restrict__ x,
                                                     const float* __restrict__ A,
                                                     short* __restrict__ Zt) {
    __shared__ __align__(16) short Xs[TTILE * 64 * XSTR];   // 25600 B
    __shared__ __align__(16) short Ats[PP * 32 * XSTR];     // 7680 B (zero-padded)

    const int tid  = threadIdx.x;
    const int lane = tid & 63;
    const int wave = tid >> 6;
    const int n  = blockIdx.x / NTILES;
    const int t0 = (blockIdx.x % NTILES) * TTILE;
    const int lg = lane >> 4;
    const int li = lane & 15;

    {   // stage X (coalesced) and At (transposed, zero-padded)
        const float* xb = x + (size_t)n * (CIN * TTOT * VV) + (size_t)t0 * VV;
        #pragma unroll
        for (int it = 0; it < 20; ++it) {                   // 20*512 = 64*5*32
            int i = tid + it * 512;
            int c = i / 160;
            int r2 = i - c * 160;
            int t = r2 >> 5, w = r2 & 31;
            float val = (w < VV) ? xb[c * (TTOT * VV) + t * VV + w] : 0.0f;
            Xs[(t * 64 + c) * XSTR + w] = f2bf(val);
        }
        #pragma unroll
        for (int it = 0; it < 8; ++it) {
            int i = tid + it * 512;
            if (i < PP * 32 * XSTR) {
                int p = i / (32 * XSTR);
                int r = i - p * (32 * XSTR);
                int v = r / XSTR, w = r - v * XSTR;
                Ats[i] = (v < VV && w < VV) ? f2bf(A[p * (VV * VV) + w * VV + v])
                                            : (short)0;
            }
        }
    }
    __syncthreads();

    const int cf = wave >> 1;          // c-frag 0..3 (c0 = cf*16)
    const int vf = wave & 1;           // v-frag 0..1
    const int vv = vf * 16 + li;       // output v within a t

    s16x8 xa[TTILE];
    #pragma unroll
    for (int t = 0; t < TTILE; ++t)
        xa[t] = *(const s16x8*)(&Xs[(t * 64 + cf * 16 + li) * XSTR + lg * 8]);
    s16x8 af[PP];
    #pragma unroll
    for (int p = 0; p < PP; ++p)
        af[p] = *(const s16x8*)(&Ats[(p * 32 + vf * 16 + li) * XSTR + lg * 8]);

    const bool vok = (vv < VV);
    const size_t colbase = (size_t)n * 7500 + (size_t)t0 * VV + vv;
    #pragma unroll
    for (int t = 0; t < TTILE; ++t) {
        #pragma unroll
        for (int p = 0; p < PP; ++p) {
            f32x4 z = (f32x4){0.f, 0.f, 0.f, 0.f};
            // A-op = X rows (M=c), B-op = At rows (N=v): D[row=c][col=v]
            f32x4 d = __builtin_amdgcn_mfma_f32_16x16x32_bf16(xa[t], af[p], z, 0, 0, 0);
            if (vok) {
                ushort4 pk;
                pk.x = (unsigned short)f2bf(d[0]);
                pk.y = (unsigned short)f2bf(d[1]);
                pk.z = (unsigned short)f2bf(d[2]);
                pk.w = (unsigned short)f2bf(d[3]);
                // rows c = cf*16 + lg*4 + r are contiguous in k
                *(ushort4*)(&Zt[(colbase + (size_t)t * VV) * KTOT
                                + p * 64 + cf * 16 + lg * 4]) = pk;
            }
        }
    }
}

// Conv GEMM: y[128, 240000] = W2[128,192] * Zt^T ; tile 128o x 128cols, full K.
// W in registers; Z staged via global_load_lds into XOR-swizzled LDS (T2/rule21).
__global__ __launch_bounds__(512, 2) void conv_kernel(const short* __restrict__ Zt,
                                                      float* __restrict__ y,
                                                      float* ws) {
    __shared__ __align__(16) short Zs[128 * KTOT];          // 49152 B
    const int tid  = threadIdx.x;
    const int lane = tid & 63;
    const int wave = tid >> 6;
    const int lg = lane >> 4;
    const int li = lane & 15;
    const int c0 = blockIdx.x * 128;

    // stage 49152B: linear LDS dest, inverse-swizzled per-lane global source.
    // chunk c (16B): col = c/24, within = (c%24)*16; src within' = within ^ ((col&7)<<4)
    {
        const char* ztb = (const char*)Zt + (size_t)c0 * 384;
        char* lbase = (char*)Zs + (size_t)wave * 64 * 16;
        #pragma unroll
        for (int it = 0; it < 6; ++it) {
            int chunk = it * 512 + tid;
            int col = chunk / 24;
            int within = (chunk - col * 24) * 16;
            int srcoff = within ^ ((col & 7) << 4);
            gl_lds16(ztb + (size_t)col * 384 + srcoff, lbase + (size_t)it * 512 * 16);
        }
    }

    // W fragments (global, L2-hot; latency overlaps staging)
    const short* w2 = (const short*)(ws + WS_W2);
    const int ow = wave >> 1;            // o0 = ow*32 (2 m-frags)
    const int ch = wave & 1;             // cols ch*64 (4 col-frags)
    const int o0 = ow * 32;
    s16x8 wf[2][6];
    #pragma unroll
    for (int mf = 0; mf < 2; ++mf)
        #pragma unroll
        for (int ks = 0; ks < 6; ++ks)
            wf[mf][ks] = *(const s16x8*)(w2 + (o0 + mf * 16 + li) * KTOT
                                            + ks * 32 + lg * 8);

    f32x4 acc[2][4];
    #pragma unroll
    for (int mf = 0; mf < 2; ++mf)
        #pragma unroll
        for (int cf = 0; cf < 4; ++cf)
            acc[mf][cf] = (f32x4){0.f, 0.f, 0.f, 0.f};

    __syncthreads();   // drains vmcnt(0): LDS tile + wf ready

    #pragma unroll
    for (int cf = 0; cf < 4; ++cf) {
        int col = ch * 64 + cf * 16 + li;
        int rb = col * 384;
        int sw = (col & 7) << 4;
        #pragma unroll
        for (int ks = 0; ks < 6; ++ks) {
            s16x8 zf = *(const s16x8*)((const char*)Zs
                                       + ((rb + ks * 64 + lg * 16) ^ sw));
            acc[0][cf] = __builtin_amdgcn_mfma_f32_16x16x32_bf16(wf[0][ks], zf,
                                                                 acc[0][cf], 0, 0, 0);
            acc[1][cf] = __builtin_amdgcn_mfma_f32_16x16x32_bf16(wf[1][ks], zf,
                                                                 acc[1][cf], 0, 0, 0);
        }
    }

    // epilogue: +bias, store y (final layout), per-channel stats
    const float* bsum = ws + WS_BSUM;
    float* stats = ws + WS_STATS;
    #pragma unroll
    for (int mf = 0; mf < 2; ++mf) {
        #pragma unroll
        for (int r = 0; r < 4; ++r) {
            int o = o0 + mf * 16 + lg * 4 + r;
            float bo = bsum[o];
            float s = 0.f, sq = 0.f;
            #pragma unroll
            for (int cf = 0; cf < 4; ++cf) {
                int col = c0 + ch * 64 + cf * 16 + li;   // global col = n*7500 + inner
                float val = acc[mf][cf][r] + bo;
                int n = col / 7500;
                int inner = col - n * 7500;
                y[(size_t)(n * COUT + o) * 7500 + inner] = val;
                s += val; sq += val * val;
            }
            #pragma unroll
            for (int m = 1; m < 16; m <<= 1) {
                s  += __shfl_xor(s, m, 64);
                sq += __shfl_xor(sq, m, 64);
            }
            if (li == 0) {
                atomicAdd(&stats[o], s);
                atomicAdd(&stats[128 + o], sq);
            }
        }
    }
}

// ---------------- fused fallback (R4, unchanged) ----------------
__global__ __launch_bounds__(512, 4) void sgcn_main(const float* __restrict__ x,
                                                    const float* __restrict__ A,
                                                    float* __restrict__ y,
                                                    float* ws) {
    __shared__ __align__(16) short Xs[TTILE * 64 * XSTR];
    __shared__ __align__(16) short Ats[PP * 32 * XSTR];
    __shared__ __align__(16) short Z2s[ZROWS * ZSTR];
    __shared__ float sstat[256];

    const int tid  = threadIdx.x;
    const int lane = tid & 63;
    const int wave = tid >> 6;
    const int n  = blockIdx.x / NTILES;
    const int t0 = (blockIdx.x % NTILES) * TTILE;
    const int lg = lane >> 4;
    const int li = lane & 15;

    {
        const float* xb = x + (size_t)n * (CIN * TTOT * VV) + (size_t)t0 * VV;
        #pragma unroll
        for (int it = 0; it < 20; ++it) {
            int i = tid + it * 512;
            int c = i / 160;
            int r2 = i - c * 160;
            int t = r2 >> 5, w = r2 & 31;
            float val = (w < VV) ? xb[c * (TTOT * VV) + t * VV + w] : 0.0f;
            Xs[(t * 64 + c) * XSTR + w] = f2bf(val);
        }
        #pragma unroll
        for (int it = 0; it < 8; ++it) {
            int i = tid + it * 512;
            if (i < PP * 32 * XSTR) {
                int p = i / (32 * XSTR);
                int r = i - p * (32 * XSTR);
                int v = r / XSTR, w = r - v * XSTR;
                Ats[i] = (v < VV && w < VV) ? f2bf(A[p * (VV * VV) + w * VV + v])
                                            : (short)0;
            }
        }
        if (tid < 108) ((int*)(Z2s + 125 * ZSTR))[tid] = 0;
        if (tid < 256) sstat[tid] = 0.0f;
    }
    __syncthreads();

    const int ow = wave >> 1;
    const int cw = wave & 1;
    const int o0 = ow * 32;
    const short* w2 = (const short*)(ws + WS_W2);

    f32x4 acc[2][4];
    #pragma unroll
    for (int mf = 0; mf < 2; ++mf)
        #pragma unroll
        for (int cf = 0; cf < 4; ++cf)
            acc[mf][cf] = (f32x4){0.f, 0.f, 0.f, 0.f};

    for (int p = 0; p < PP; ++p) {
        s16x8 wfl[2][2];
        #pragma unroll
        for (int mf = 0; mf < 2; ++mf)
            #pragma unroll
            for (int ks = 0; ks < 2; ++ks)
                wfl[mf][ks] = *(const s16x8*)(w2 + (o0 + mf * 16 + li) * KTOT
                                                 + p * 64 + ks * 32 + lg * 8);
        #pragma unroll
        for (int q = 0; q < 5; ++q) {
            int f = wave * 5 + q;
            int t = f >> 3, rem = f & 7;
            int vf = rem >> 2, cfr = rem & 3;
            s16x8 af = *(const s16x8*)(&Ats[(p * 32 + vf * 16 + li) * XSTR + lg * 8]);
            s16x8 bf = *(const s16x8*)(&Xs[(t * 64 + cfr * 16 + li) * XSTR + lg * 8]);
            f32x4 z = (f32x4){0.f, 0.f, 0.f, 0.f};
            f32x4 d = __builtin_amdgcn_mfma_f32_16x16x32_bf16(af, bf, z, 0, 0, 0);
            int m0 = vf * 16 + lg * 4;
            int ccol = cfr * 16 + li;
            #pragma unroll
            for (int r = 0; r < 4; ++r) {
                int m = m0 + r;
                if (m < VV) Z2s[(t * VV + m) * ZSTR + ccol] = f2bf(d[r]);
            }
        }
        __syncthreads();
        #pragma unroll
        for (int cf = 0; cf < 4; ++cf) {
            int col0 = cw * 64 + cf * 16;
            #pragma unroll
            for (int ks = 0; ks < 2; ++ks) {
                s16x8 zf = *(const s16x8*)(&Z2s[(col0 + li) * ZSTR + ks * 32 + lg * 8]);
                #pragma unroll
                for (int mf = 0; mf < 2; ++mf)
                    acc[mf][cf] = __builtin_amdgcn_mfma_f32_16x16x32_bf16(
                        wfl[mf][ks], zf, acc[mf][cf], 0, 0, 0);
            }
        }
        __syncthreads();
    }

    const float* bsum = ws + WS_BSUM;
    #pragma unroll
    for (int mf = 0; mf < 2; ++mf) {
        #pragma unroll
        for (int r = 0; r < 4; ++r) {
            int o = o0 + mf * 16 + lg * 4 + r;
            float bo = bsum[o];
            float s = 0.f, sq = 0.f;
            #pragma unroll
            for (int cf = 0; cf < 4; ++cf) {
                int col = cw * 64 + cf * 16 + li;
                float val = acc[mf][cf][r] + bo;
                if (col < TTILE * VV) {
                    y[(size_t)(n * COUT + o) * (TTOT * VV) + t0 * VV + col] = val;
                    s += val; sq += val * val;
                }
            }
            #pragma unroll
            for (int m = 1; m < 16; m <<= 1) {
                s  += __shfl_xor(s, m, 64);
                sq += __shfl_xor(sq, m, 64);
            }
            if (li == 0) {
                atomicAdd(&sstat[o], s);
                atomicAdd(&sstat[128 + o], sq);
            }
        }
    }
    __syncthreads();
    if (tid < 256) atomicAdd(&ws[WS_STATS + tid], sstat[tid]);
}

// ---------------- shared tail ----------------
__global__ void finalize_kernel(const float* __restrict__ gamma,
                                const float* __restrict__ beta,
                                float* ws) {
    int o = threadIdx.x;  // 128 threads
    float mean = ws[WS_STATS + o] * (1.0f / CNT);
    float ex2  = ws[WS_STATS + 128 + o] * (1.0f / CNT);
    float var  = ex2 - mean * mean;
    float rstd = rsqrtf(var + 1e-5f);
    float sc = gamma[o] * rstd;
    ws[WS_SCALE + o] = sc;
    ws[WS_SHIFT + o] = beta[o] - mean * sc;
}

__global__ __launch_bounds__(256) void norm_relu_kernel(float* __restrict__ y,
                                                        const float* __restrict__ ws) {
    const int total8 = (NN * COUT * TTOT * VV) / 8;
    const float* scale = ws + WS_SCALE;
    const float* shift = ws + WS_SHIFT;
    for (int i = blockIdx.x * blockDim.x + threadIdx.x; i < total8;
         i += gridDim.x * blockDim.x) {
        size_t base = (size_t)i * 8;
        int row0 = (int)(base / 7500);
        int row1 = (int)((base + 7) / 7500);
        int o0 = row0 & 127, o1 = row1 & 127;
        float s0 = scale[o0], h0 = shift[o0];
        float s1 = scale[o1], h1 = shift[o1];
        size_t bnd = (size_t)(row0 + 1) * 7500;
        float4 a = *(const float4*)(y + base);
        float4 b = *(const float4*)(y + base + 4);
        float vals[8] = {a.x, a.y, a.z, a.w, b.x, b.y, b.z, b.w};
        #pragma unroll
        for (int e = 0; e < 8; ++e) {
            bool first = (base + (size_t)e) < bnd;
            float s = first ? s0 : s1;
            float h = first ? h0 : h1;
            vals[e] = fmaxf(vals[e] * s + h, 0.0f);
        }
        a = make_float4(vals[0], vals[1], vals[2], vals[3]);
        b = make_float4(vals[4], vals[5], vals[6], vals[7]);
        *(float4*)(y + base) = a;
        *(float4*)(y + base + 4) = b;
    }
}

extern "C" void kernel_launch(void* const* d_in, const int* in_sizes, int n_in,
                              void* d_out, int out_size, void* d_ws, size_t ws_size,
                              hipStream_t stream) {
    const float* x     = (const float*)d_in[0];
    const float* A     = (const float*)d_in[1];
    const float* W     = (const float*)d_in[2];
    const float* b     = (const float*)d_in[3];
    const float* gamma = (const float*)d_in[4];
    const float* beta  = (const float*)d_in[5];
    float* y  = (float*)d_out;
    float* ws = (float*)d_ws;

    prep_kernel<<<96, 256, 0, stream>>>(W, b, ws);
    if (ws_size >= WS_NEEDED) {
        short* Zt = (short*)((char*)d_ws + ZT_BYTE_OFF);
        agg_kernel<<<NN * NTILES, 512, 0, stream>>>(x, A, Zt);
        conv_kernel<<<NCOLS / 128, 512, 0, stream>>>(Zt, y, ws);
    } else {
        sgcn_main<<<NN * NTILES, 512, 0, stream>>>(x, A, y, ws);
    }
    finalize_kernel<<<1, 128, 0, stream>>>(gamma, beta, ws);
    norm_relu_kernel<<<2048, 256, 0, stream>>>(y, ws);
}

// Round 6
// 171.741 us; speedup vs baseline: 2.7889x; 2.7889x over previous
//
#include <hip/hip_runtime.h>
#include <hip/hip_bf16.h>

#define NN 32
#define CIN 64
#define TTOT 300
#define VV 25
#define PP 3
#define COUT 128
#define KTOT 192     // P*CIN
#define TTILE 5
#define NTILES 60
#define CNT 240000.0f
#define NCOLS 240000 // N*T*V
#define SBLK 375     // conv_stats grid (375*5 tiles = 1875)

#define XSTR 40      // X/At w-stride in shorts: 80B rows -> 2-way banks, 16B aligned
#define ZSTR 72      // fused-path Z2 c-stride
#define ZROWS 128

// ws float offsets (front region < 1 MB)
#define WS_STATS 0    // 256 f32 (fallback path only)
#define WS_SCALE 256  // 128 f32
#define WS_SHIFT 384  // 128 f32
#define WS_BSUM  512  // 128 f32
#define WS_W2    640  // bf16[128*192]; W2[o][p*64+c]
#define WS_PART  32768            // f32[375][256]: per-block partial sum/sq (384 KB)
#define ZT_BYTE_OFF (1u << 20)    // Zt bf16[240000][192] at +1MB
#define WS_NEEDED (ZT_BYTE_OFF + (size_t)NCOLS * KTOT * 2)

typedef float f32x4 __attribute__((ext_vector_type(4)));
typedef short s16x8 __attribute__((ext_vector_type(8)));

__device__ __forceinline__ short f2bf(float f) {
    unsigned u = __float_as_uint(f);
    u += 0x7fff + ((u >> 16) & 1);          // RNE
    return (short)(u >> 16);
}

__device__ __forceinline__ void gl_lds16(const void* g, void* l) {
    __builtin_amdgcn_global_load_lds(
        (const __attribute__((address_space(1))) unsigned int*)g,
        (__attribute__((address_space(3))) unsigned int*)l, 16, 0, 0);
}

__global__ __launch_bounds__(256) void prep_kernel(const float* __restrict__ W,
                                                   const float* __restrict__ b,
                                                   float* __restrict__ ws) {
    int tid = blockIdx.x * blockDim.x + threadIdx.x;
    if (tid < 256) ws[WS_STATS + tid] = 0.0f;               // fallback path zeroing
    if (tid >= 256 && tid < 384) {
        int o = tid - 256;
        ws[WS_BSUM + o] = b[o] + b[COUT + o] + b[2 * COUT + o];
    }
    if (tid < COUT * KTOT) {                                 // W2[o][k], k = p*64+c
        int o = tid / KTOT, k = tid % KTOT;
        int p = k / 64, c = k % 64;
        ((short*)(ws + WS_W2))[tid] = f2bf(W[(p * COUT + o) * CIN + c]);
    }
}

// ---------------- fast path ----------------

// Aggregation: Zt[col=(n*300+t)*25+v][k=p*64+c] = bf16( sum_w x[n,c,t,w]*A[p,w,v] )
__global__ __launch_bounds__(512, 4) void agg_kernel(const float* __restrict__ x,
                                                     const float* __restrict__ A,
                                                     short* __restrict__ Zt) {
    __shared__ __align__(16) short Xs[TTILE * 64 * XSTR];   // 25600 B
    __shared__ __align__(16) short Ats[PP * 32 * XSTR];     // 7680 B (zero-padded)

    const int tid  = threadIdx.x;
    const int lane = tid & 63;
    const int wave = tid >> 6;
    const int n  = blockIdx.x / NTILES;
    const int t0 = (blockIdx.x % NTILES) * TTILE;
    const int lg = lane >> 4;
    const int li = lane & 15;

    {   // stage X (coalesced) and At (transposed, zero-padded)
        const float* xb = x + (size_t)n * (CIN * TTOT * VV) + (size_t)t0 * VV;
        #pragma unroll
        for (int it = 0; it < 20; ++it) {                   // 20*512 = 64*5*32
            int i = tid + it * 512;
            int c = i / 160;
            int r2 = i - c * 160;
            int t = r2 >> 5, w = r2 & 31;
            float val = (w < VV) ? xb[c * (TTOT * VV) + t * VV + w] : 0.0f;
            Xs[(t * 64 + c) * XSTR + w] = f2bf(val);
        }
        #pragma unroll
        for (int it = 0; it < 8; ++it) {
            int i = tid + it * 512;
            if (i < PP * 32 * XSTR) {
                int p = i / (32 * XSTR);
                int r = i - p * (32 * XSTR);
                int v = r / XSTR, w = r - v * XSTR;
                Ats[i] = (v < VV && w < VV) ? f2bf(A[p * (VV * VV) + w * VV + v])
                                            : (short)0;
            }
        }
    }
    __syncthreads();

    const int cf = wave >> 1;          // c-frag 0..3
    const int vf = wave & 1;           // v-frag 0..1
    const int vv = vf * 16 + li;

    s16x8 xa[TTILE];
    #pragma unroll
    for (int t = 0; t < TTILE; ++t)
        xa[t] = *(const s16x8*)(&Xs[(t * 64 + cf * 16 + li) * XSTR + lg * 8]);
    s16x8 af[PP];
    #pragma unroll
    for (int p = 0; p < PP; ++p)
        af[p] = *(const s16x8*)(&Ats[(p * 32 + vf * 16 + li) * XSTR + lg * 8]);

    const bool vok = (vv < VV);
    const size_t colbase = (size_t)n * 7500 + (size_t)t0 * VV + vv;
    #pragma unroll
    for (int t = 0; t < TTILE; ++t) {
        #pragma unroll
        for (int p = 0; p < PP; ++p) {
            f32x4 z = (f32x4){0.f, 0.f, 0.f, 0.f};
            f32x4 d = __builtin_amdgcn_mfma_f32_16x16x32_bf16(xa[t], af[p], z, 0, 0, 0);
            if (vok) {
                ushort4 pk;
                pk.x = (unsigned short)f2bf(d[0]);
                pk.y = (unsigned short)f2bf(d[1]);
                pk.z = (unsigned short)f2bf(d[2]);
                pk.w = (unsigned short)f2bf(d[3]);
                *(ushort4*)(&Zt[(colbase + (size_t)t * VV) * KTOT
                                + p * 64 + cf * 16 + lg * 4]) = pk;
            }
        }
    }
}

// conv_stats: Zt -> per-block partial sum/sumsq (NO y write, NO atomics).
// grid SBLK blocks x 5 column-tiles of 128.
__global__ __launch_bounds__(512, 4) void conv_stats(const short* __restrict__ Zt,
                                                     float* __restrict__ ws) {
    __shared__ __align__(16) short Zs[128 * KTOT];          // 49152 B
    __shared__ float sstat[256];
    const int tid  = threadIdx.x;
    const int lane = tid & 63;
    const int wave = tid >> 6;
    const int lg = lane >> 4;
    const int li = lane & 15;
    const int blk = blockIdx.x;

    const short* w2 = (const short*)(ws + WS_W2);
    const float* bsum = ws + WS_BSUM;
    const int ow = wave >> 1;
    const int ch = wave & 1;
    const int o0 = ow * 32;

    s16x8 wf[2][6];
    #pragma unroll
    for (int mf = 0; mf < 2; ++mf)
        #pragma unroll
        for (int ks = 0; ks < 6; ++ks)
            wf[mf][ks] = *(const s16x8*)(w2 + (o0 + mf * 16 + li) * KTOT
                                            + ks * 32 + lg * 8);

    if (tid < 256) sstat[tid] = 0.0f;

    float s[2][4], sq[2][4];
    #pragma unroll
    for (int mf = 0; mf < 2; ++mf)
        #pragma unroll
        for (int r = 0; r < 4; ++r) { s[mf][r] = 0.f; sq[mf][r] = 0.f; }

    #pragma unroll 1
    for (int ti = 0; ti < 5; ++ti) {
        const int c0 = (blk * 5 + ti) * 128;
        {   // stage: linear LDS dest, inverse-swizzled per-lane global source
            const char* ztb = (const char*)Zt + (size_t)c0 * 384;
            char* lb = (char*)Zs + (size_t)wave * 1024;
            #pragma unroll
            for (int it = 0; it < 6; ++it) {
                int chunk = it * 512 + tid;
                int col = chunk / 24;
                int within = (chunk - col * 24) * 16;
                int srcoff = within ^ ((col & 7) << 4);
                gl_lds16(ztb + (size_t)col * 384 + srcoff, lb + (size_t)it * 8192);
            }
        }
        __syncthreads();   // drains vmcnt(0)

        f32x4 acc[2][4];
        #pragma unroll
        for (int mf = 0; mf < 2; ++mf)
            #pragma unroll
            for (int cf = 0; cf < 4; ++cf)
                acc[mf][cf] = (f32x4){0.f, 0.f, 0.f, 0.f};

        #pragma unroll
        for (int cf = 0; cf < 4; ++cf) {
            int col = ch * 64 + cf * 16 + li;
            int rb = col * 384;
            int sw = (col & 7) << 4;
            #pragma unroll
            for (int ks = 0; ks < 6; ++ks) {
                s16x8 zf = *(const s16x8*)((const char*)Zs
                                           + ((rb + ks * 64 + lg * 16) ^ sw));
                acc[0][cf] = __builtin_amdgcn_mfma_f32_16x16x32_bf16(wf[0][ks], zf,
                                                                     acc[0][cf], 0, 0, 0);
                acc[1][cf] = __builtin_amdgcn_mfma_f32_16x16x32_bf16(wf[1][ks], zf,
                                                                     acc[1][cf], 0, 0, 0);
            }
        }

        #pragma unroll
        for (int mf = 0; mf < 2; ++mf) {
            #pragma unroll
            for (int r = 0; r < 4; ++r) {
                float bo = bsum[o0 + mf * 16 + lg * 4 + r];
                #pragma unroll
                for (int cf = 0; cf < 4; ++cf) {
                    float val = acc[mf][cf][r] + bo;
                    s[mf][r] += val;
                    sq[mf][r] += val * val;
                }
            }
        }
        __syncthreads();   // before next tile's staging overwrites Zs
    }

    // reduce over li (16 lanes share (o)); LDS-atomic across waves; plain store
    #pragma unroll
    for (int mf = 0; mf < 2; ++mf) {
        #pragma unroll
        for (int r = 0; r < 4; ++r) {
            float a = s[mf][r], b = sq[mf][r];
            #pragma unroll
            for (int m = 1; m < 16; m <<= 1) {
                a += __shfl_xor(a, m, 64);
                b += __shfl_xor(b, m, 64);
            }
            if (li == 0) {
                int o = o0 + mf * 16 + lg * 4 + r;
                atomicAdd(&sstat[o], a);          // LDS atomic (cheap)
                atomicAdd(&sstat[128 + o], b);
            }
        }
    }
    __syncthreads();
    if (tid < 256) ws[WS_PART + blk * 256 + tid] = sstat[tid];  // coalesced 1KB store
}

__global__ void finalize_partials(const float* __restrict__ gamma,
                                  const float* __restrict__ beta,
                                  float* ws) {
    // 128 blocks x 128 threads: block o; wave0 sums sum-partials, wave1 sumsq
    __shared__ float red[2];
    const int o = blockIdx.x;
    const int wave = threadIdx.x >> 6;
    const int lane = threadIdx.x & 63;
    float acc = 0.f;
    #pragma unroll
    for (int it = 0; it < 6; ++it) {
        int blk = lane + it * 64;
        if (blk < SBLK) acc += ws[WS_PART + blk * 256 + wave * 128 + o];
    }
    #pragma unroll
    for (int m = 1; m < 64; m <<= 1) acc += __shfl_xor(acc, m, 64);
    if (lane == 0) red[wave] = acc;
    __syncthreads();
    if (threadIdx.x == 0) {
        float mean = red[0] * (1.0f / CNT);
        float ex2  = red[1] * (1.0f / CNT);
        float var  = ex2 - mean * mean;
        float rstd = rsqrtf(var + 1e-5f);
        float sc = gamma[o] * rstd;
        ws[WS_SCALE + o] = sc;
        ws[WS_SHIFT + o] = beta[o] - mean * sc;
    }
}

// conv_apply: Zt -> y final (BN+ReLU fused). grid 1875.
__global__ __launch_bounds__(512, 4) void conv_apply(const short* __restrict__ Zt,
                                                     float* __restrict__ y,
                                                     const float* __restrict__ ws) {
    __shared__ __align__(16) short Zs[128 * KTOT];          // 49152 B
    const int tid  = threadIdx.x;
    const int lane = tid & 63;
    const int wave = tid >> 6;
    const int lg = lane >> 4;
    const int li = lane & 15;
    const int c0 = blockIdx.x * 128;

    {
        const char* ztb = (const char*)Zt + (size_t)c0 * 384;
        char* lb = (char*)Zs + (size_t)wave * 1024;
        #pragma unroll
        for (int it = 0; it < 6; ++it) {
            int chunk = it * 512 + tid;
            int col = chunk / 24;
            int within = (chunk - col * 24) * 16;
            int srcoff = within ^ ((col & 7) << 4);
            gl_lds16(ztb + (size_t)col * 384 + srcoff, lb + (size_t)it * 8192);
        }
    }

    const short* w2 = (const short*)(ws + WS_W2);
    const int ow = wave >> 1;
    const int ch = wave & 1;
    const int o0 = ow * 32;
    s16x8 wf[2][6];
    #pragma unroll
    for (int mf = 0; mf < 2; ++mf)
        #pragma unroll
        for (int ks = 0; ks < 6; ++ks)
            wf[mf][ks] = *(const s16x8*)(w2 + (o0 + mf * 16 + li) * KTOT
                                            + ks * 32 + lg * 8);

    f32x4 acc[2][4];
    #pragma unroll
    for (int mf = 0; mf < 2; ++mf)
        #pragma unroll
        for (int cf = 0; cf < 4; ++cf)
            acc[mf][cf] = (f32x4){0.f, 0.f, 0.f, 0.f};

    __syncthreads();   // drains vmcnt(0)

    #pragma unroll
    for (int cf = 0; cf < 4; ++cf) {
        int col = ch * 64 + cf * 16 + li;
        int rb = col * 384;
        int sw = (col & 7) << 4;
        #pragma unroll
        for (int ks = 0; ks < 6; ++ks) {
            s16x8 zf = *(const s16x8*)((const char*)Zs
                                       + ((rb + ks * 64 + lg * 16) ^ sw));
            acc[0][cf] = __builtin_amdgcn_mfma_f32_16x16x32_bf16(wf[0][ks], zf,
                                                                 acc[0][cf], 0, 0, 0);
            acc[1][cf] = __builtin_amdgcn_mfma_f32_16x16x32_bf16(wf[1][ks], zf,
                                                                 acc[1][cf], 0, 0, 0);
        }
    }

    const float* bsum = ws + WS_BSUM;
    const float* scale = ws + WS_SCALE;
    const float* shift = ws + WS_SHIFT;
    #pragma unroll
    for (int mf = 0; mf < 2; ++mf) {
        float4 scv = *(const float4*)(scale + o0 + mf * 16 + lg * 4);
        float4 shv = *(const float4*)(shift + o0 + mf * 16 + lg * 4);
        float4 bov = *(const float4*)(bsum  + o0 + mf * 16 + lg * 4);
        float scr[4] = {scv.x, scv.y, scv.z, scv.w};
        float shr[4] = {shv.x, shv.y, shv.z, shv.w};
        float bor[4] = {bov.x, bov.y, bov.z, bov.w};
        #pragma unroll
        for (int r = 0; r < 4; ++r) {
            int o = o0 + mf * 16 + lg * 4 + r;
            #pragma unroll
            for (int cf = 0; cf < 4; ++cf) {
                int col = c0 + ch * 64 + cf * 16 + li;
                float val = acc[mf][cf][r] + bor[r];
                val = fmaxf(val * scr[r] + shr[r], 0.0f);
                int n = col / 7500;
                int inner = col - n * 7500;
                y[(size_t)(n * COUT + o) * 7500 + inner] = val;
            }
        }
    }
}

// ---------------- fused fallback (R4) + tail, used only if ws too small ----------------
__global__ __launch_bounds__(512, 4) void sgcn_main(const float* __restrict__ x,
                                                    const float* __restrict__ A,
                                                    float* __restrict__ y,
                                                    float* ws) {
    __shared__ __align__(16) short Xs[TTILE * 64 * XSTR];
    __shared__ __align__(16) short Ats[PP * 32 * XSTR];
    __shared__ __align__(16) short Z2s[ZROWS * ZSTR];
    __shared__ float sstat[256];

    const int tid  = threadIdx.x;
    const int lane = tid & 63;
    const int wave = tid >> 6;
    const int n  = blockIdx.x / NTILES;
    const int t0 = (blockIdx.x % NTILES) * TTILE;
    const int lg = lane >> 4;
    const int li = lane & 15;

    {
        const float* xb = x + (size_t)n * (CIN * TTOT * VV) + (size_t)t0 * VV;
        #pragma unroll
        for (int it = 0; it < 20; ++it) {
            int i = tid + it * 512;
            int c = i / 160;
            int r2 = i - c * 160;
            int t = r2 >> 5, w = r2 & 31;
            float val = (w < VV) ? xb[c * (TTOT * VV) + t * VV + w] : 0.0f;
            Xs[(t * 64 + c) * XSTR + w] = f2bf(val);
        }
        #pragma unroll
        for (int it = 0; it < 8; ++it) {
            int i = tid + it * 512;
            if (i < PP * 32 * XSTR) {
                int p = i / (32 * XSTR);
                int r = i - p * (32 * XSTR);
                int v = r / XSTR, w = r - v * XSTR;
                Ats[i] = (v < VV && w < VV) ? f2bf(A[p * (VV * VV) + w * VV + v])
                                            : (short)0;
            }
        }
        if (tid < 108) ((int*)(Z2s + 125 * ZSTR))[tid] = 0;
        if (tid < 256) sstat[tid] = 0.0f;
    }
    __syncthreads();

    const int ow = wave >> 1;
    const int cw = wave & 1;
    const int o0 = ow * 32;
    const short* w2 = (const short*)(ws + WS_W2);

    f32x4 acc[2][4];
    #pragma unroll
    for (int mf = 0; mf < 2; ++mf)
        #pragma unroll
        for (int cf = 0; cf < 4; ++cf)
            acc[mf][cf] = (f32x4){0.f, 0.f, 0.f, 0.f};

    for (int p = 0; p < PP; ++p) {
        s16x8 wfl[2][2];
        #pragma unroll
        for (int mf = 0; mf < 2; ++mf)
            #pragma unroll
            for (int ks = 0; ks < 2; ++ks)
                wfl[mf][ks] = *(const s16x8*)(w2 + (o0 + mf * 16 + li) * KTOT
                                                 + p * 64 + ks * 32 + lg * 8);
        #pragma unroll
        for (int q = 0; q < 5; ++q) {
            int f = wave * 5 + q;
            int t = f >> 3, rem = f & 7;
            int vf = rem >> 2, cfr = rem & 3;
            s16x8 af = *(const s16x8*)(&Ats[(p * 32 + vf * 16 + li) * XSTR + lg * 8]);
            s16x8 bf = *(const s16x8*)(&Xs[(t * 64 + cfr * 16 + li) * XSTR + lg * 8]);
            f32x4 z = (f32x4){0.f, 0.f, 0.f, 0.f};
            f32x4 d = __builtin_amdgcn_mfma_f32_16x16x32_bf16(af, bf, z, 0, 0, 0);
            int m0 = vf * 16 + lg * 4;
            int ccol = cfr * 16 + li;
            #pragma unroll
            for (int r = 0; r < 4; ++r) {
                int m = m0 + r;
                if (m < VV) Z2s[(t * VV + m) * ZSTR + ccol] = f2bf(d[r]);
            }
        }
        __syncthreads();
        #pragma unroll
        for (int cf = 0; cf < 4; ++cf) {
            int col0 = cw * 64 + cf * 16;
            #pragma unroll
            for (int ks = 0; ks < 2; ++ks) {
                s16x8 zf = *(const s16x8*)(&Z2s[(col0 + li) * ZSTR + ks * 32 + lg * 8]);
                #pragma unroll
                for (int mf = 0; mf < 2; ++mf)
                    acc[mf][cf] = __builtin_amdgcn_mfma_f32_16x16x32_bf16(
                        wfl[mf][ks], zf, acc[mf][cf], 0, 0, 0);
            }
        }
        __syncthreads();
    }

    const float* bsum = ws + WS_BSUM;
    #pragma unroll
    for (int mf = 0; mf < 2; ++mf) {
        #pragma unroll
        for (int r = 0; r < 4; ++r) {
            int o = o0 + mf * 16 + lg * 4 + r;
            float bo = bsum[o];
            float s = 0.f, sq = 0.f;
            #pragma unroll
            for (int cf = 0; cf < 4; ++cf) {
                int col = cw * 64 + cf * 16 + li;
                float val = acc[mf][cf][r] + bo;
                if (col < TTILE * VV) {
                    y[(size_t)(n * COUT + o) * (TTOT * VV) + t0 * VV + col] = val;
                    s += val; sq += val * val;
                }
            }
            #pragma unroll
            for (int m = 1; m < 16; m <<= 1) {
                s  += __shfl_xor(s, m, 64);
                sq += __shfl_xor(sq, m, 64);
            }
            if (li == 0) {
                atomicAdd(&sstat[o], s);
                atomicAdd(&sstat[128 + o], sq);
            }
        }
    }
    __syncthreads();
    if (tid < 256) atomicAdd(&ws[WS_STATS + tid], sstat[tid]);
}

__global__ void finalize_kernel(const float* __restrict__ gamma,
                                const float* __restrict__ beta,
                                float* ws) {
    int o = threadIdx.x;
    float mean = ws[WS_STATS + o] * (1.0f / CNT);
    float ex2  = ws[WS_STATS + 128 + o] * (1.0f / CNT);
    float var  = ex2 - mean * mean;
    float rstd = rsqrtf(var + 1e-5f);
    float sc = gamma[o] * rstd;
    ws[WS_SCALE + o] = sc;
    ws[WS_SHIFT + o] = beta[o] - mean * sc;
}

__global__ __launch_bounds__(256) void norm_relu_kernel(float* __restrict__ y,
                                                        const float* __restrict__ ws) {
    const int total8 = (NN * COUT * TTOT * VV) / 8;
    const float* scale = ws + WS_SCALE;
    const float* shift = ws + WS_SHIFT;
    for (int i = blockIdx.x * blockDim.x + threadIdx.x; i < total8;
         i += gridDim.x * blockDim.x) {
        size_t base = (size_t)i * 8;
        int row0 = (int)(base / 7500);
        int row1 = (int)((base + 7) / 7500);
        int o0 = row0 & 127, o1 = row1 & 127;
        float s0 = scale[o0], h0 = shift[o0];
        float s1 = scale[o1], h1 = shift[o1];
        size_t bnd = (size_t)(row0 + 1) * 7500;
        float4 a = *(const float4*)(y + base);
        float4 b = *(const float4*)(y + base + 4);
        float vals[8] = {a.x, a.y, a.z, a.w, b.x, b.y, b.z, b.w};
        #pragma unroll
        for (int e = 0; e < 8; ++e) {
            bool first = (base + (size_t)e) < bnd;
            float sv = first ? s0 : s1;
            float hv = first ? h0 : h1;
            vals[e] = fmaxf(vals[e] * sv + hv, 0.0f);
        }
        a = make_float4(vals[0], vals[1], vals[2], vals[3]);
        b = make_float4(vals[4], vals[5], vals[6], vals[7]);
        *(float4*)(y + base) = a;
        *(float4*)(y + base + 4) = b;
    }
}

extern "C" void kernel_launch(void* const* d_in, const int* in_sizes, int n_in,
                              void* d_out, int out_size, void* d_ws, size_t ws_size,
                              hipStream_t stream) {
    const float* x     = (const float*)d_in[0];
    const float* A     = (const float*)d_in[1];
    const float* W     = (const float*)d_in[2];
    const float* b     = (const float*)d_in[3];
    const float* gamma = (const float*)d_in[4];
    const float* beta  = (const float*)d_in[5];
    float* y  = (float*)d_out;
    float* ws = (float*)d_ws;

    prep_kernel<<<96, 256, 0, stream>>>(W, b, ws);
    if (ws_size >= WS_NEEDED) {
        short* Zt = (short*)((char*)d_ws + ZT_BYTE_OFF);
        agg_kernel<<<NN * NTILES, 512, 0, stream>>>(x, A, Zt);
        conv_stats<<<SBLK, 512, 0, stream>>>(Zt, ws);
        finalize_partials<<<COUT, 128, 0, stream>>>(gamma, beta, ws);
        conv_apply<<<NCOLS / 128, 512, 0, stream>>>(Zt, y, ws);
    } else {
        sgcn_main<<<NN * NTILES, 512, 0, stream>>>(x, A, y, ws);
        finalize_kernel<<<1, 128, 0, stream>>>(gamma, beta, ws);
        norm_relu_kernel<<<2048, 256, 0, stream>>>(y, ws);
    }
}